// Round 1
// baseline (1348.786 us; speedup 1.0000x reference)
//
#include <hip/hip_runtime.h>
#include <hip/hip_bf16.h>

#define N_ROWS   16384
#define IN_DIM_  512
#define EMBED_   256

// ---------------- Kernel 1: rowsum -> d ----------------
// One 256-thread block per row. Each thread: 16 float4 loads (coalesced),
// then wave shuffle reduce + LDS reduce across 4 waves.
__global__ __launch_bounds__(256) void rowsum_kernel(const float* __restrict__ adj,
                                                     float* __restrict__ d) {
    const int row = blockIdx.x;
    const float4* rp = (const float4*)(adj + (size_t)row * N_ROWS);
    float s = 0.f;
#pragma unroll
    for (int j = 0; j < 16; ++j) {
        float4 v = rp[threadIdx.x + j * 256];
        s += (v.x + v.y) + (v.z + v.w);
    }
    // reduce across the 64-lane wave
#pragma unroll
    for (int off = 32; off > 0; off >>= 1) s += __shfl_down(s, off, 64);
    __shared__ float ws[4];
    const int lane = threadIdx.x & 63, wid = threadIdx.x >> 6;
    if (lane == 0) ws[wid] = s;
    __syncthreads();
    if (threadIdx.x == 0) {
        float t = (ws[0] + ws[1]) + (ws[2] + ws[3]);
        d[row] = 1.0f / (t + 1.0f) + 1.0f;
    }
}

// ---------------- Kernel 2: out = relu(d[n] * (x @ W^T)) ----------------
// M=16384, K=512, E=256. BLOCK_M=32, BLOCK_E=256 (full width), 256 thr = 4 waves.
// Wave w computes rows [0,32) x cols [64w, 64w+64) via 2x4 grid of 16x16x32 bf16 MFMA.

typedef __attribute__((ext_vector_type(8))) short bf16x8;
typedef __attribute__((ext_vector_type(4))) float f32x4;

#define BK 32
#define SA 40  // padded LDS row stride in shorts (80 B: 16B-aligned, breaks pow2 banks)

__device__ inline short f2bf(float f) {
    __hip_bfloat16 h = __float2bfloat16(f);
    return __builtin_bit_cast(short, h);
}

__device__ inline void store_bf4(short* p, float4 v) {
    short4 h;
    h.x = f2bf(v.x); h.y = f2bf(v.y); h.z = f2bf(v.z); h.w = f2bf(v.w);
    *(short4*)p = h;
}

__global__ __launch_bounds__(256) void gemm_kernel(const float* __restrict__ x,
                                                   const float* __restrict__ W,
                                                   const float* __restrict__ d,
                                                   float* __restrict__ out) {
    __shared__ short As[32 * SA];    // 32 rows x BK bf16 (padded)
    __shared__ short Bs[256 * SA];   // 256 rows (E) x BK bf16 (padded)

    const int t    = threadIdx.x;
    const int wave = t >> 6;
    const int lane = t & 63;
    const int l16  = lane & 15;
    const int quad = lane >> 4;       // 0..3
    const int row0 = blockIdx.x * 32;
    const int e0   = wave * 64;

    // A staging map: 32 rows x 8 float4/row = 256 float4 -> 1 per thread
    const int ra = t >> 3, ka = t & 7;

    f32x4 acc[2][4];
#pragma unroll
    for (int i = 0; i < 2; ++i)
#pragma unroll
        for (int j = 0; j < 4; ++j) acc[i][j] = (f32x4){0.f, 0.f, 0.f, 0.f};

    for (int kb = 0; kb < IN_DIM_; kb += BK) {
        // ---- global loads (fp32) ----
        float4 va = *(const float4*)(x + (size_t)(row0 + ra) * IN_DIM_ + kb + ka * 4);
        float4 vb[8];
#pragma unroll
        for (int i = 0; i < 8; ++i) {
            int f = t + i * 256;
            int rb = f >> 3, kq = f & 7;
            vb[i] = *(const float4*)(W + (size_t)rb * IN_DIM_ + kb + kq * 4);
        }
        // ---- convert + LDS store (bf16) ----
        store_bf4(&As[ra * SA + ka * 4], va);
#pragma unroll
        for (int i = 0; i < 8; ++i) {
            int f = t + i * 256;
            int rb = f >> 3, kq = f & 7;
            store_bf4(&Bs[rb * SA + kq * 4], vb[i]);
        }
        __syncthreads();

        // ---- fragments + MFMA ----
        bf16x8 af[2], bfr[4];
#pragma unroll
        for (int mi = 0; mi < 2; ++mi)
            af[mi] = *(const bf16x8*)(&As[(mi * 16 + l16) * SA + quad * 8]);
#pragma unroll
        for (int ni = 0; ni < 4; ++ni)
            bfr[ni] = *(const bf16x8*)(&Bs[(e0 + ni * 16 + l16) * SA + quad * 8]);
#pragma unroll
        for (int mi = 0; mi < 2; ++mi)
#pragma unroll
            for (int ni = 0; ni < 4; ++ni)
                acc[mi][ni] = __builtin_amdgcn_mfma_f32_16x16x32_bf16(
                    af[mi], bfr[ni], acc[mi][ni], 0, 0, 0);
        __syncthreads();
    }

    // ---- epilogue: scale by d[row], ReLU, store ----
    // C/D layout: col = lane&15, row = (lane>>4)*4 + reg
#pragma unroll
    for (int mi = 0; mi < 2; ++mi) {
#pragma unroll
        for (int r = 0; r < 4; ++r) {
            int grow = row0 + mi * 16 + quad * 4 + r;
            float dv = d[grow];
#pragma unroll
            for (int ni = 0; ni < 4; ++ni) {
                float v = acc[mi][ni][r] * dv;
                out[(size_t)grow * EMBED_ + e0 + ni * 16 + l16] = v > 0.f ? v : 0.f;
            }
        }
    }
}

extern "C" void kernel_launch(void* const* d_in, const int* in_sizes, int n_in,
                              void* d_out, int out_size, void* d_ws, size_t ws_size,
                              hipStream_t stream) {
    const float* adj = (const float*)d_in[0];
    const float* x   = (const float*)d_in[1];
    const float* W   = (const float*)d_in[2];
    float* out = (float*)d_out;
    float* dvec = (float*)d_ws;  // 16384 floats = 64 KiB scratch

    rowsum_kernel<<<N_ROWS, 256, 0, stream>>>(adj, dvec);
    gemm_kernel<<<N_ROWS / 32, 256, 0, stream>>>(x, W, dvec, out);
}